// Round 1
// baseline (607.294 us; speedup 1.0000x reference)
//
#include <hip/hip_runtime.h>
#include <math.h>

#define DIM 128
#define KCODES 1024
#define NROWS 65536

// ---- workspace float layout ----
#define WS_ENORM  0        // 1024 floats: 0.5*||e_k||^2
#define WS_COUNTS 1024     // 1024 floats: batch cluster counts
#define WS_ESUM   2048     // 131072 floats: embed_sum (segment sum of x)
#define WS_TOTAL  133120   // 1 float: sum(new_cluster_size)

// ---- output float layout (concatenated in reference return order) ----
#define OFF_Q   0                         // quantize: 8*8192*128 = 8388608
#define OFF_IND 8388608                   // embed_ind: 65536
#define OFF_NCS 8454144                   // new_cluster_size: 1024
#define OFF_NEA 8455168                   // new_embed_avg: 131072
#define OFF_NE  8586240                   // new_embed: 131072

// ============ kernel 1: half squared norms of codebook rows ============
__global__ __launch_bounds__(64) void k_enorm(const float* __restrict__ embed,
                                              float* __restrict__ ws) {
    int k = blockIdx.x;
    int lane = threadIdx.x;  // 0..63
    float2 v = *(const float2*)&embed[(size_t)k * DIM + lane * 2];
    float s = v.x * v.x + v.y * v.y;
    #pragma unroll
    for (int off = 32; off; off >>= 1) s += __shfl_xor(s, off);
    if (lane == 0) ws[WS_ENORM + k] = 0.5f * s;
}

// ============ kernel 2: fp32 scoring + per-row top-2 candidates ============
// block = 256 threads, tile = 64 rows x 64 codes, micro-tile 4x4 per thread.
#define ROWS 64
#define TC 64

__device__ __forceinline__ void ins2(float s, int c, float& M1, int& I1,
                                     float& M2, int& I2) {
    bool b1 = (s > M1) || (s == M1 && c < I1);
    bool b2 = (s > M2) || (s == M2 && c < I2);
    if (b1) { M2 = M1; I2 = I1; M1 = s; I1 = c; }
    else if (b2) { M2 = s; I2 = c; }
}

__global__ __launch_bounds__(256) void k_score(const float* __restrict__ x,
                                               const float* __restrict__ embed,
                                               const float* __restrict__ enorm,
                                               unsigned int* __restrict__ top2out) {
    // smem: xT[128][64] (32KB) + eT[128][64] (32KB); merge scratch overlays xT.
    __shared__ float smem[DIM * ROWS + DIM * TC];
    float* xT = smem;
    float* eT = smem + DIM * ROWS;
    float* red = smem;  // reused after compute: [64 rows][stride 68]

    const int tid = threadIdx.x;
    const int row0 = blockIdx.x * ROWS;

    // stage x tile transposed, conflict-free: lane -> row, groups -> dims
    {
        int r = tid & 63;
        int dg = tid >> 6;  // 0..3
        #pragma unroll
        for (int it = 0; it < 8; ++it) {
            int d0 = dg * 4 + it * 16;
            float4 v = *(const float4*)&x[(size_t)(row0 + r) * DIM + d0];
            xT[(d0 + 0) * ROWS + r] = v.x;
            xT[(d0 + 1) * ROWS + r] = v.y;
            xT[(d0 + 2) * ROWS + r] = v.z;
            xT[(d0 + 3) * ROWS + r] = v.w;
        }
    }

    const int tx = tid & 15;   // code group
    const int ty = tid >> 4;   // row group (0..15)

    float m1[4], m2[4];
    int i1[4], i2[4];
    #pragma unroll
    for (int i = 0; i < 4; ++i) { m1[i] = -INFINITY; m2[i] = -INFINITY; i1[i] = 0; i2[i] = 0; }

    for (int ct = 0; ct < KCODES / TC; ++ct) {
        const int c0 = ct * TC;
        __syncthreads();  // previous tile's eT reads done
        {
            int c = tid & 63;
            int dg = tid >> 6;
            #pragma unroll
            for (int it = 0; it < 8; ++it) {
                int d0 = dg * 4 + it * 16;
                float4 v = *(const float4*)&embed[(size_t)(c0 + c) * DIM + d0];
                eT[(d0 + 0) * TC + c] = v.x;
                eT[(d0 + 1) * TC + c] = v.y;
                eT[(d0 + 2) * TC + c] = v.z;
                eT[(d0 + 3) * TC + c] = v.w;
            }
        }
        __syncthreads();

        float acc[4][4] = {};
        #pragma unroll 4
        for (int k = 0; k < DIM; ++k) {
            const float4 a = *(const float4*)(xT + k * ROWS + ty * 4);
            const float4 b = *(const float4*)(eT + k * TC + tx * 4);
            const float av[4] = {a.x, a.y, a.z, a.w};
            const float bv[4] = {b.x, b.y, b.z, b.w};
            #pragma unroll
            for (int i = 0; i < 4; ++i)
                #pragma unroll
                for (int j = 0; j < 4; ++j)
                    acc[i][j] = fmaf(av[i], bv[j], acc[i][j]);
        }

        // score = x.e - 0.5*||e||^2 ; update running top-2 (ascending code order)
        #pragma unroll
        for (int j = 0; j < 4; ++j) {
            int c = c0 + tx * 4 + j;
            float en = enorm[c];
            #pragma unroll
            for (int i = 0; i < 4; ++i) {
                float s = acc[i][j] - en;
                bool b1 = s > m1[i];
                bool b2 = s > m2[i];
                m2[i] = b1 ? m1[i] : (b2 ? s : m2[i]);
                i2[i] = b1 ? i1[i] : (b2 ? c : i2[i]);
                m1[i] = b1 ? s : m1[i];
                i1[i] = b1 ? c : i1[i];
            }
        }
    }

    // cross-thread merge: 16 tx-threads hold candidates for each row
    __syncthreads();
    #pragma unroll
    for (int i = 0; i < 4; ++i) {
        int rl = ty * 4 + i;
        float* p = &red[rl * 68 + tx * 4];
        p[0] = m1[i];
        p[1] = __int_as_float(i1[i]);
        p[2] = m2[i];
        p[3] = __int_as_float(i2[i]);
    }
    __syncthreads();
    if (tid < ROWS) {
        int rl = tid;
        float M1 = -INFINITY, M2 = -INFINITY;
        int I1 = 0, I2 = 0;
        #pragma unroll
        for (int t = 0; t < 16; ++t) {
            const float* p = &red[rl * 68 + t * 4];
            ins2(p[0], __float_as_int(p[1]), M1, I1, M2, I2);
            ins2(p[2], __float_as_int(p[3]), M1, I1, M2, I2);
        }
        top2out[row0 + rl] = (unsigned)I1 | ((unsigned)I2 << 16);
    }
}

// ============ kernel 3: fp64 rescore of top-2, quantize write, scatter ============
// one wave per row; 256 threads = 4 rows per block
__global__ __launch_bounds__(256) void k_scatter(const float* __restrict__ x,
                                                 const float* __restrict__ embed,
                                                 float* __restrict__ out,
                                                 float* __restrict__ ws) {
    const int lane = threadIdx.x & 63;
    const int row = blockIdx.x * 4 + (threadIdx.x >> 6);

    const unsigned* top2 = (const unsigned*)(out + OFF_IND);
    unsigned p = top2[row];
    int ca = (int)(p & 0xffffu);
    int cb = (int)(p >> 16);

    float2 xv = *(const float2*)&x[(size_t)row * DIM + lane * 2];
    float2 e1 = *(const float2*)&embed[(size_t)ca * DIM + lane * 2];
    float2 e2 = *(const float2*)&embed[(size_t)cb * DIM + lane * 2];

    double dxa = (double)xv.x - (double)e1.x;
    double dya = (double)xv.y - (double)e1.y;
    double dxb = (double)xv.x - (double)e2.x;
    double dyb = (double)xv.y - (double)e2.y;
    double d1 = dxa * dxa + dya * dya;
    double d2 = dxb * dxb + dyb * dyb;
    #pragma unroll
    for (int off = 32; off; off >>= 1) {
        d1 += __shfl_xor(d1, off);
        d2 += __shfl_xor(d2, off);
    }

    bool pick2 = (d2 < d1) || (d2 == d1 && cb < ca);
    int win = pick2 ? cb : ca;
    float2 ew = pick2 ? e2 : e1;

    *(float2*)&out[OFF_Q + (size_t)row * DIM + lane * 2] = ew;

    atomicAdd(&ws[WS_ESUM + win * DIM + lane * 2], xv.x);
    atomicAdd(&ws[WS_ESUM + win * DIM + lane * 2 + 1], xv.y);
    if (lane == 0) {
        atomicAdd(&ws[WS_COUNTS + win], 1.0f);
        out[OFF_IND + row] = (float)win;
    }
}

// ============ kernel 4: new_cluster_size + total ============
__global__ __launch_bounds__(1024) void k_ncs(const float* __restrict__ cs,
                                              float* __restrict__ out,
                                              float* __restrict__ ws) {
    __shared__ float sred[1024];
    int t = threadIdx.x;
    float ncs = cs[t] * 0.99f + 0.01f * ws[WS_COUNTS + t];
    out[OFF_NCS + t] = ncs;
    sred[t] = ncs;
    __syncthreads();
    for (int s = 512; s; s >>= 1) {
        if (t < s) sred[t] += sred[t + s];
        __syncthreads();
    }
    if (t == 0) ws[WS_TOTAL] = sred[0];
}

// ============ kernel 5: new_embed_avg + new_embed ============
__global__ __launch_bounds__(256) void k_embed(const float* __restrict__ ea,
                                               const float* __restrict__ ws,
                                               float* __restrict__ out) {
    int i = blockIdx.x * 256 + threadIdx.x;  // < 131072
    int k = i >> 7;
    float nea = ea[i] * 0.99f + 0.01f * ws[WS_ESUM + i];
    out[OFF_NEA + i] = nea;
    float total = ws[WS_TOTAL];
    float ncs = out[OFF_NCS + k];
    float sm = (ncs + 1e-5f) / (total + 1024.0f * 1e-5f);
    out[OFF_NE + i] = nea / (sm * total);
}

extern "C" void kernel_launch(void* const* d_in, const int* in_sizes, int n_in,
                              void* d_out, int out_size, void* d_ws, size_t ws_size,
                              hipStream_t stream) {
    const float* x     = (const float*)d_in[0];
    const float* embed = (const float*)d_in[1];
    const float* cs    = (const float*)d_in[2];
    const float* ea    = (const float*)d_in[3];
    float* out = (float*)d_out;
    float* ws  = (float*)d_ws;

    // zero counts + embed_sum (contiguous region)
    hipMemsetAsync((char*)d_ws + WS_COUNTS * 4, 0, (size_t)(1024 + 131072) * 4, stream);

    k_enorm<<<KCODES, 64, 0, stream>>>(embed, ws);
    k_score<<<NROWS / ROWS, 256, 0, stream>>>(x, embed, ws + WS_ENORM,
                                              (unsigned int*)(out + OFF_IND));
    k_scatter<<<NROWS / 4, 256, 0, stream>>>(x, embed, out, ws);
    k_ncs<<<1, 1024, 0, stream>>>(cs, out, ws);
    k_embed<<<131072 / 256, 256, 0, stream>>>(ea, ws, out);
}

// Round 2
// 261.868 us; speedup vs baseline: 2.3191x; 2.3191x over previous
//
#include <hip/hip_runtime.h>
#include <math.h>

#define DIM 128
#define KCODES 1024
#define NROWS 65536

typedef short bf16x8 __attribute__((ext_vector_type(8)));
typedef float f32x4 __attribute__((ext_vector_type(4)));

// ---- workspace float-index layout ----
#define WS_ENORM2 0        // 1024 f: 512 - 0.5*||e||^2
#define WS_COUNTS 1024     // 1024 f
#define WS_ESUM   2048     // 131072 f
#define WS_TOTAL  133120   // 1 f
#define WS_EBF    133128   // 131072 bf16 (= 65536 float slots), 16B aligned
#define WS_CAND   198664   // 65536 uint4, 16B aligned

// ---- output float layout ----
#define OFF_Q   0
#define OFF_IND 8388608
#define OFF_NCS 8454144
#define OFF_NEA 8455168
#define OFF_NE  8586240

#define LDST 136  // LDS row stride in bf16 units (128 + 8 pad)

static __device__ __forceinline__ unsigned short f2bf(float f) {
    unsigned u = __float_as_uint(f);
    unsigned r = (u + 0x7FFFu + ((u >> 16) & 1u)) >> 16;  // RTN-even
    return (unsigned short)r;
}

// ============ kernel 1: embed -> bf16 copy + shifted half-norms ============
__global__ __launch_bounds__(64) void k_prep(const float* __restrict__ embed,
                                             unsigned short* __restrict__ ebf,
                                             float* __restrict__ en2) {
    int k = blockIdx.x;
    int l = threadIdx.x;
    float2 v = *(const float2*)&embed[(size_t)k * DIM + l * 2];
    ushort2 b;
    b.x = f2bf(v.x);
    b.y = f2bf(v.y);
    *(ushort2*)&ebf[k * DIM + l * 2] = b;
    float s = v.x * v.x + v.y * v.y;
    #pragma unroll
    for (int off = 32; off; off >>= 1) s += __shfl_xor(s, off);
    if (l == 0) en2[k] = 512.0f - 0.5f * s;
}

// ============ kernel 2: MFMA scoring, 4 candidates per row ============
// 512 blocks x 256 threads. Block tile: 128 rows x (all 1024 codes, 8 tiles of 128).
// Wave quadrant: 64 rows x 64 codes via 4x4 tiles of mfma_f32_16x16x32_bf16.
__global__ __launch_bounds__(256, 2) void k_score(const float* __restrict__ x,
                                                  const unsigned short* __restrict__ ebf,
                                                  const float* __restrict__ en2g,
                                                  uint4* __restrict__ cand) {
    __shared__ unsigned short xbuf[128 * LDST];
    __shared__ unsigned short ebuf[128 * LDST];
    __shared__ float en2s[KCODES];

    const int tid = threadIdx.x;
    const int row0 = blockIdx.x * 128;

    #pragma unroll
    for (int i = 0; i < 4; ++i) en2s[i * 256 + tid] = en2g[i * 256 + tid];

    // stage x tile: fp32 global -> bf16 LDS (row-major, padded stride)
    #pragma unroll
    for (int i = 0; i < 16; ++i) {
        int idx4 = i * 256 + tid;           // float4 index within 128x128 tile
        int lin = idx4 * 4;
        int r = lin >> 7, d = lin & 127;
        float4 v = *(const float4*)&x[(size_t)(row0 + r) * DIM + d];
        ushort4 b;
        b.x = f2bf(v.x); b.y = f2bf(v.y); b.z = f2bf(v.z); b.w = f2bf(v.w);
        *(ushort4*)&xbuf[r * LDST + d] = b;
    }

    const int lane = tid & 63;
    const int wv = tid >> 6;
    const int ch = wv & 1;          // code half within 128-code tile
    const int rh = (wv >> 1) * 64;  // row half
    const int l15 = lane & 15;
    const int q = lane >> 4;

    float m1[4][4], m2[4][4];  // [rt][reg] running top-2 keys
    #pragma unroll
    for (int a = 0; a < 4; ++a)
        #pragma unroll
        for (int b = 0; b < 4; ++b) { m1[a][b] = 0.0f; m2[a][b] = 0.0f; }

    for (int ct = 0; ct < 8; ++ct) {
        const int c0 = ct * 128;
        __syncthreads();  // previous tile's ebuf reads done (also covers x staging on ct=0)
        #pragma unroll
        for (int i = 0; i < 8; ++i) {
            int idx8 = i * 256 + tid;       // 8-short chunk index (2048 total)
            int r = idx8 >> 4;
            int d = (idx8 & 15) * 8;
            uint4 v = *(const uint4*)&ebf[(size_t)(c0 + r) * DIM + d];
            *(uint4*)&ebuf[r * LDST + d] = v;
        }
        __syncthreads();

        f32x4 acc[4][4];
        #pragma unroll
        for (int a = 0; a < 4; ++a)
            #pragma unroll
            for (int b = 0; b < 4; ++b) acc[a][b] = (f32x4){0.f, 0.f, 0.f, 0.f};

        #pragma unroll
        for (int ks = 0; ks < 4; ++ks) {
            bf16x8 af[4], bf[4];
            #pragma unroll
            for (int t = 0; t < 4; ++t)
                af[t] = *(const bf16x8*)&xbuf[(rh + t * 16 + l15) * LDST + ks * 32 + q * 8];
            #pragma unroll
            for (int t = 0; t < 4; ++t)
                bf[t] = *(const bf16x8*)&ebuf[(ch * 64 + t * 16 + l15) * LDST + ks * 32 + q * 8];
            #pragma unroll
            for (int rt = 0; rt < 4; ++rt)
                #pragma unroll
                for (int cl = 0; cl < 4; ++cl)
                    acc[rt][cl] = __builtin_amdgcn_mfma_f32_16x16x32_bf16(af[rt], bf[cl],
                                                                          acc[rt][cl], 0, 0, 0);
        }

        // epilogue: fold en', embed code index into mantissa LSBs, keep top-2 keys
        #pragma unroll
        for (int cl = 0; cl < 4; ++cl) {
            int code = c0 + ch * 64 + cl * 16 + l15;
            float en = en2s[code];
            unsigned cu = (unsigned)code;
            #pragma unroll
            for (int rt = 0; rt < 4; ++rt)
                #pragma unroll
                for (int rg = 0; rg < 4; ++rg) {
                    float s = acc[rt][cl][rg] + en;  // in (0, ~900), positive
                    float kf = __uint_as_float((__float_as_uint(s) & ~1023u) | cu);
                    float lo = fminf(m1[rt][rg], kf);
                    m1[rt][rg] = fmaxf(m1[rt][rg], kf);
                    m2[rt][rg] = fmaxf(m2[rt][rg], lo);
                }
        }
    }

    // merge across the 16 code-lanes of each quad group
    __syncthreads();  // all waves done reading xbuf/ebuf; xbuf becomes scratch
    float* scratch = (float*)xbuf;  // [128 rows][4 keys]
    #pragma unroll
    for (int rt = 0; rt < 4; ++rt)
        #pragma unroll
        for (int rg = 0; rg < 4; ++rg) {
            float a1 = m1[rt][rg], a2 = m2[rt][rg];
            #pragma unroll
            for (int off = 1; off <= 8; off <<= 1) {
                float o1 = __shfl_xor(a1, off);
                float o2 = __shfl_xor(a2, off);
                float lo = fminf(a1, o1);
                a1 = fmaxf(a1, o1);
                a2 = fmaxf(fmaxf(a2, o2), lo);
            }
            if (l15 == 0) {
                int row = rh + rt * 16 + q * 4 + rg;
                scratch[row * 4 + ch * 2 + 0] = a1;
                scratch[row * 4 + ch * 2 + 1] = a2;
            }
        }
    __syncthreads();
    if (tid < 128) {
        const float* p = &scratch[tid * 4];
        uint4 c;
        c.x = __float_as_uint(p[0]) & 1023u;
        c.y = __float_as_uint(p[1]) & 1023u;
        c.z = __float_as_uint(p[2]) & 1023u;
        c.w = __float_as_uint(p[3]) & 1023u;
        cand[row0 + tid] = c;
    }
}

// ============ kernel 3: fp64 exact rescore of 4 candidates + scatter ============
__global__ __launch_bounds__(256) void k_scatter(const float* __restrict__ x,
                                                 const float* __restrict__ embed,
                                                 const uint4* __restrict__ cand,
                                                 float* __restrict__ out,
                                                 float* __restrict__ ws) {
    const int lane = threadIdx.x & 63;
    const int row = blockIdx.x * 4 + (threadIdx.x >> 6);

    uint4 cp = cand[row];
    int ci[4] = {(int)cp.x, (int)cp.y, (int)cp.z, (int)cp.w};

    float2 xv = *(const float2*)&x[(size_t)row * DIM + lane * 2];
    float2 ev[4];
    double d[4];
    #pragma unroll
    for (int j = 0; j < 4; ++j) {
        ev[j] = *(const float2*)&embed[(size_t)ci[j] * DIM + lane * 2];
        double dx = (double)xv.x - (double)ev[j].x;
        double dy = (double)xv.y - (double)ev[j].y;
        d[j] = dx * dx + dy * dy;
    }
    #pragma unroll
    for (int off = 32; off; off >>= 1) {
        #pragma unroll
        for (int j = 0; j < 4; ++j) d[j] += __shfl_xor(d[j], off);
    }

    int win = ci[0];
    double dw = d[0];
    float2 ew = ev[0];
    #pragma unroll
    for (int j = 1; j < 4; ++j) {
        bool b = (d[j] < dw) || (d[j] == dw && ci[j] < win);
        dw = b ? d[j] : dw;
        win = b ? ci[j] : win;
        ew = b ? ev[j] : ew;
    }

    *(float2*)&out[OFF_Q + (size_t)row * DIM + lane * 2] = ew;

    atomicAdd(&ws[WS_ESUM + win * DIM + lane * 2], xv.x);
    atomicAdd(&ws[WS_ESUM + win * DIM + lane * 2 + 1], xv.y);
    if (lane == 0) {
        atomicAdd(&ws[WS_COUNTS + win], 1.0f);
        out[OFF_IND + row] = (float)win;
    }
}

// ============ kernel 4: new_cluster_size + total ============
__global__ __launch_bounds__(1024) void k_ncs(const float* __restrict__ cs,
                                              float* __restrict__ out,
                                              float* __restrict__ ws) {
    __shared__ float sred[1024];
    int t = threadIdx.x;
    float ncs = cs[t] * 0.99f + 0.01f * ws[WS_COUNTS + t];
    out[OFF_NCS + t] = ncs;
    sred[t] = ncs;
    __syncthreads();
    for (int s = 512; s; s >>= 1) {
        if (t < s) sred[t] += sred[t + s];
        __syncthreads();
    }
    if (t == 0) ws[WS_TOTAL] = sred[0];
}

// ============ kernel 5: new_embed_avg + new_embed ============
__global__ __launch_bounds__(256) void k_embed(const float* __restrict__ ea,
                                               const float* __restrict__ ws,
                                               float* __restrict__ out) {
    int i = blockIdx.x * 256 + threadIdx.x;
    int k = i >> 7;
    float nea = ea[i] * 0.99f + 0.01f * ws[WS_ESUM + i];
    out[OFF_NEA + i] = nea;
    float total = ws[WS_TOTAL];
    float ncs = out[OFF_NCS + k];
    float sm = (ncs + 1e-5f) / (total + 1024.0f * 1e-5f);
    out[OFF_NE + i] = nea / (sm * total);
}

extern "C" void kernel_launch(void* const* d_in, const int* in_sizes, int n_in,
                              void* d_out, int out_size, void* d_ws, size_t ws_size,
                              hipStream_t stream) {
    const float* x     = (const float*)d_in[0];
    const float* embed = (const float*)d_in[1];
    const float* cs    = (const float*)d_in[2];
    const float* ea    = (const float*)d_in[3];
    float* out = (float*)d_out;
    float* ws  = (float*)d_ws;

    // zero counts + embed_sum (contiguous floats [1024, 133120))
    hipMemsetAsync((char*)d_ws + WS_COUNTS * 4, 0, (size_t)(1024 + 131072) * 4, stream);

    k_prep<<<KCODES, 64, 0, stream>>>(embed, (unsigned short*)(ws + WS_EBF), ws + WS_ENORM2);
    k_score<<<NROWS / 128, 256, 0, stream>>>(x, (const unsigned short*)(ws + WS_EBF),
                                             ws + WS_ENORM2, (uint4*)(ws + WS_CAND));
    k_scatter<<<NROWS / 4, 256, 0, stream>>>(x, embed, (const uint4*)(ws + WS_CAND), out, ws);
    k_ncs<<<1, 1024, 0, stream>>>(cs, out, ws);
    k_embed<<<131072 / 256, 256, 0, stream>>>(ea, ws, out);
}